// Round 1
// 1042.387 us; speedup vs baseline: 1.1746x; 1.1746x over previous
//
#include <hip/hip_runtime.h>
#include <hip/hip_bf16.h>
#include <math.h>

#define T_TOK 1024
#define DDIM  1024
#define FDIM  2048
#define NEXP  32
#define KTOP  4
#define ESH   33       // 32 routed experts + shared as e=32
#define RTOT  5120     // 4096 routed rows + 1024 shared rows

// workspace layout (int units)
#define WS_CNT   0      // 32 ints (must be zeroed)
#define WS_NWORK 32     // 1
#define WS_OFF   34     // 34
#define WS_WL    68     // up to 256 work tiles
#define WS_TOPI  324    // 4096
#define WS_TOPW  4420   // 4096
#define WS_LTOK  8516   // 5120
#define WS_LW    13636  // 5120
#define WS_H     18816  // bf16 H[5120][2048] starts at byte 4*WS_H

typedef __attribute__((ext_vector_type(8))) short short8;
typedef __attribute__((ext_vector_type(4))) float f32x4;

__device__ inline unsigned pack_bf16x2(float a, float b) {
  unsigned ua = __float_as_uint(a), ub = __float_as_uint(b);
  ua = (ua + 0x8000u) >> 16;
  ub = (ub + 0x8000u) & 0xFFFF0000u;
  return ua | ub;
}

// ---------------- router: logits, top-4, softmax, counts ----------------
__global__ void k_router(const float* __restrict__ x, const float* __restrict__ gw,
                         const float* __restrict__ bias, int* __restrict__ ws) {
  int t = blockIdx.x;
  int lane = threadIdx.x;           // 64
  int e = lane & 31, half = lane >> 5;
  const float* xh = x + (size_t)t * DDIM + half * (DDIM / 2);
  const float* gr = gw + (size_t)e * DDIM + half * (DDIM / 2);
  float acc = 0.f;
  for (int d = 0; d < DDIM / 2; d += 4) {
    float4 xv = *(const float4*)(xh + d);
    float4 gv = *(const float4*)(gr + d);
    acc += xv.x * gv.x + xv.y * gv.y + xv.z * gv.z + xv.w * gv.w;
  }
  acc += __shfl_xor(acc, 32, 64);
  __shared__ float lg[NEXP];
  if (lane < NEXP) lg[lane] = acc + bias[lane];
  __syncthreads();
  if (lane == 0) {
    int idx[KTOP]; float val[KTOP]; unsigned used = 0;
    for (int s = 0; s < KTOP; ++s) {
      float best = -1e30f; int bi = 0;
      for (int j = 0; j < NEXP; ++j)
        if (!((used >> j) & 1u) && lg[j] > best) { best = lg[j]; bi = j; }
      used |= 1u << bi; idx[s] = bi; val[s] = best;
    }
    float m = val[0], ssum = 0.f, w[KTOP];
    for (int s = 0; s < KTOP; ++s) { w[s] = __expf(val[s] - m); ssum += w[s]; }
    for (int s = 0; s < KTOP; ++s) {
      ws[WS_TOPI + t * KTOP + s] = idx[s];
      ((float*)ws)[WS_TOPW + t * KTOP + s] = w[s] / ssum;
      atomicAdd(&ws[WS_CNT + idx[s]], 1);
    }
  }
}

// ---------------- post: offsets, worklist (256-row tiles), token lists ----------------
__global__ void k_post(int* __restrict__ ws, float* __restrict__ out) {
  __shared__ int off_s[ESH + 1];
  __shared__ int cur_s[ESH];
  int tid = threadIdx.x;
  if (tid == 0) {
    int o = 0;
    for (int e = 0; e < NEXP; ++e) { off_s[e] = o; o += ws[WS_CNT + e]; }
    off_s[32] = o; off_s[33] = o + T_TOK;
    int w = 0;
    for (int e = 0; e < ESH; ++e) {
      int n = (e < NEXP) ? ws[WS_CNT + e] : T_TOK;
      int tiles = (n + 255) >> 8;
      for (int mt = 0; mt < tiles; ++mt) ws[WS_WL + w++] = (e << 6) | mt;
    }
    ws[WS_NWORK] = w;
    for (int i = 0; i <= ESH; ++i) ws[WS_OFF + i] = off_s[i];
    float mean = 0.f;
    for (int e = 0; e < NEXP; ++e) mean += (float)ws[WS_CNT + e];
    mean *= (1.f / NEXP);
    float var = 0.f;
    for (int e = 0; e < NEXP; ++e) { float d = (float)ws[WS_CNT + e] - mean; var += d * d; }
    var *= (1.f / NEXP);
    for (int e = 0; e < NEXP; ++e) out[(size_t)T_TOK * DDIM + e] = (float)ws[WS_CNT + e];
    out[(size_t)T_TOK * DDIM + NEXP] = sqrtf(var) / (mean + 1e-6f);
  }
  if (tid < ESH) cur_s[tid] = 0;
  __syncthreads();
  if (tid < T_TOK) {
    for (int s = 0; s < KTOP; ++s) {
      int e = ws[WS_TOPI + tid * KTOP + s];
      int p = atomicAdd(&cur_s[e], 1);
      ws[WS_LTOK + off_s[e] + p] = tid;
      ((float*)ws)[WS_LW + off_s[e] + p] = ((const float*)ws)[WS_TOPW + tid * KTOP + s];
    }
    ws[WS_LTOK + off_s[32] + tid] = tid;
    ((float*)ws)[WS_LW + off_s[32] + tid] = 1.f;
  }
}

// ---------------- stage1: H = silu(X Wg^T) * (X Wu^T), BM=256 ----------------
__global__ __launch_bounds__(512, 4) void k_stage1(
    const float* __restrict__ x, const float* __restrict__ wg, const float* __restrict__ wu,
    const float* __restrict__ wsg, const float* __restrict__ wsu,
    const int* __restrict__ ws, __hip_bfloat16* __restrict__ H) {
  int wid = blockIdx.x;
  if (wid >= ws[WS_NWORK]) return;
  int wl = ws[WS_WL + wid];
  int e = wl >> 6, mt = wl & 63;
  int off_e = ws[WS_OFF + e];
  int n_e = ws[WS_OFF + e + 1] - off_e;
  int m0 = off_e + mt * 256;
  int rloc = n_e - mt * 256;           // valid rows in this tile (may exceed 256; guard is lrow<rloc)
  int nb = blockIdx.y * 64;
  const float* wgp = (e < NEXP) ? wg + (size_t)e * FDIM * DDIM : wsg;
  const float* wup = (e < NEXP) ? wu + (size_t)e * FDIM * DDIM : wsu;

  __shared__ int tok_s[256];
  __shared__ ushort a_s[256][64];     // row-major, 128B rows, XOR chunk swizzle
  __shared__ ushort bg_s[64][64];
  __shared__ ushort bu_s[64][64];

  int tid = threadIdx.x;
  if (tid < 256) {
    int idx = mt * 256 + tid;
    tok_s[tid] = ws[WS_LTOK + off_e + (idx < n_e ? idx : 0)];
  }
  __syncthreads();

  int kg = tid & 7;          // 16B chunk within 64-wide k slice
  int rB = tid >> 3;         // 0..63
  int wave = tid >> 6, lane = tid & 63;
  int wm = wave >> 1, wn = wave & 1;   // 4 m-waves x 2 n-waves
  int lm = lane & 15, lk = lane >> 4;

  f32x4 accg[4][2], accu[4][2];
#pragma unroll
  for (int a = 0; a < 4; ++a)
#pragma unroll
    for (int b = 0; b < 2; ++b) {
      accg[a][b] = (f32x4){0.f, 0.f, 0.f, 0.f};
      accu[a][b] = (f32x4){0.f, 0.f, 0.f, 0.f};
    }

  unsigned aoff[4];
#pragma unroll
  for (int i = 0; i < 4; ++i)
    aoff[i] = (unsigned)tok_s[rB + i * 64] * (DDIM * 4) + kg * 32;
  unsigned boff = (unsigned)(nb + rB) * (DDIM * 4) + kg * 32;

  for (int k0 = 0; k0 < DDIM; k0 += 64) {
#pragma unroll
    for (int i = 0; i < 4; ++i) {
      int m = rB + i * 64;
      float4 f0 = *(const float4*)((const char*)x + aoff[i] + k0 * 4);
      float4 f1 = *(const float4*)((const char*)x + aoff[i] + k0 * 4 + 16);
      uint4 p; p.x = pack_bf16x2(f0.x, f0.y); p.y = pack_bf16x2(f0.z, f0.w);
      p.z = pack_bf16x2(f1.x, f1.y); p.w = pack_bf16x2(f1.z, f1.w);
      *(uint4*)&a_s[m][(kg ^ (m & 7)) << 3] = p;
    }
    {
      float4 f0 = *(const float4*)((const char*)wgp + boff + k0 * 4);
      float4 f1 = *(const float4*)((const char*)wgp + boff + k0 * 4 + 16);
      uint4 p; p.x = pack_bf16x2(f0.x, f0.y); p.y = pack_bf16x2(f0.z, f0.w);
      p.z = pack_bf16x2(f1.x, f1.y); p.w = pack_bf16x2(f1.z, f1.w);
      *(uint4*)&bg_s[rB][(kg ^ (rB & 7)) << 3] = p;
      f0 = *(const float4*)((const char*)wup + boff + k0 * 4);
      f1 = *(const float4*)((const char*)wup + boff + k0 * 4 + 16);
      p.x = pack_bf16x2(f0.x, f0.y); p.y = pack_bf16x2(f0.z, f0.w);
      p.z = pack_bf16x2(f1.x, f1.y); p.w = pack_bf16x2(f1.z, f1.w);
      *(uint4*)&bu_s[rB][(kg ^ (rB & 7)) << 3] = p;
    }
    __syncthreads();
#pragma unroll
    for (int ks = 0; ks < 2; ++ks) {
      int c = ks * 4 + lk;
      short8 av[4];
#pragma unroll
      for (int mf = 0; mf < 4; ++mf) {
        int row = wm * 64 + mf * 16 + lm;
        av[mf] = *(short8*)&a_s[row][(c ^ (row & 7)) << 3];
      }
      int n0 = wn * 32 + lm;
      int sw = (c ^ (n0 & 7)) << 3;    // n0+16 has same (row&7)
      short8 bg0 = *(short8*)&bg_s[n0][sw];
      short8 bg1 = *(short8*)&bg_s[n0 + 16][sw];
#pragma unroll
      for (int mf = 0; mf < 4; ++mf) {
        accg[mf][0] = __builtin_amdgcn_mfma_f32_16x16x32_bf16(av[mf], bg0, accg[mf][0], 0, 0, 0);
        accg[mf][1] = __builtin_amdgcn_mfma_f32_16x16x32_bf16(av[mf], bg1, accg[mf][1], 0, 0, 0);
      }
      short8 bu0 = *(short8*)&bu_s[n0][sw];
      short8 bu1 = *(short8*)&bu_s[n0 + 16][sw];
#pragma unroll
      for (int mf = 0; mf < 4; ++mf) {
        accu[mf][0] = __builtin_amdgcn_mfma_f32_16x16x32_bf16(av[mf], bu0, accu[mf][0], 0, 0, 0);
        accu[mf][1] = __builtin_amdgcn_mfma_f32_16x16x32_bf16(av[mf], bu1, accu[mf][1], 0, 0, 0);
      }
    }
    __syncthreads();
  }
#pragma unroll
  for (int mf = 0; mf < 4; ++mf)
#pragma unroll
    for (int nf = 0; nf < 2; ++nf)
#pragma unroll
      for (int r = 0; r < 4; ++r) {
        int lrow = wm * 64 + mf * 16 + lk * 4 + r;
        if (lrow < rloc) {
          float gv = accg[mf][nf][r];
          float hv = (gv / (1.f + __expf(-gv))) * accu[mf][nf][r];
          H[(size_t)(m0 + lrow) * FDIM + nb + wn * 32 + nf * 16 + lm] = __float2bfloat16(hv);
        }
      }
}

// ---------------- stage2: Y = H Wd^T, weighted scatter-add, BM=256 ----------------
__global__ __launch_bounds__(512, 4) void k_stage2(
    const float* __restrict__ wd, const float* __restrict__ wsd,
    const int* __restrict__ ws, const __hip_bfloat16* __restrict__ H,
    float* __restrict__ out) {
  int wid = blockIdx.x;
  if (wid >= ws[WS_NWORK]) return;
  int wl = ws[WS_WL + wid];
  int e = wl >> 6, mt = wl & 63;
  int off_e = ws[WS_OFF + e];
  int n_e = ws[WS_OFF + e + 1] - off_e;
  int m0 = off_e + mt * 256;
  int rloc = n_e - mt * 256;
  int nb = blockIdx.y * 64;
  const float* wdp = (e < NEXP) ? wd + (size_t)e * DDIM * FDIM : wsd;

  __shared__ int tok_s[256];
  __shared__ float w_s[256];
  __shared__ ushort a_s[256][64];
  __shared__ ushort b_s[64][64];

  int tid = threadIdx.x;
  if (tid < 256) {
    int idx = mt * 256 + tid;
    int cl = idx < n_e ? idx : 0;
    tok_s[tid] = ws[WS_LTOK + off_e + cl];
    w_s[tid]   = ((const float*)ws)[WS_LW + off_e + cl];
  }
  __syncthreads();

  int kg = tid & 7;
  int rB = tid >> 3;
  int wave = tid >> 6, lane = tid & 63;
  int wm = wave >> 1, wn = wave & 1;
  int lm = lane & 15, lk = lane >> 4;

  f32x4 acc[4][2];
#pragma unroll
  for (int a = 0; a < 4; ++a)
#pragma unroll
    for (int b = 0; b < 2; ++b) acc[a][b] = (f32x4){0.f, 0.f, 0.f, 0.f};

  unsigned aoff[4];
#pragma unroll
  for (int i = 0; i < 4; ++i)
    aoff[i] = (unsigned)(m0 + rB + i * 64) * (FDIM * 2) + kg * 16;
  unsigned boff = (unsigned)(nb + rB) * (FDIM * 4) + kg * 32;

  for (int k0 = 0; k0 < FDIM; k0 += 64) {
#pragma unroll
    for (int i = 0; i < 4; ++i) {
      int m = rB + i * 64;
      uint4 p = *(const uint4*)((const char*)H + aoff[i] + k0 * 2);
      *(uint4*)&a_s[m][(kg ^ (m & 7)) << 3] = p;
    }
    {
      float4 f0 = *(const float4*)((const char*)wdp + boff + k0 * 4);
      float4 f1 = *(const float4*)((const char*)wdp + boff + k0 * 4 + 16);
      uint4 p; p.x = pack_bf16x2(f0.x, f0.y); p.y = pack_bf16x2(f0.z, f0.w);
      p.z = pack_bf16x2(f1.x, f1.y); p.w = pack_bf16x2(f1.z, f1.w);
      *(uint4*)&b_s[rB][(kg ^ (rB & 7)) << 3] = p;
    }
    __syncthreads();
#pragma unroll
    for (int ks = 0; ks < 2; ++ks) {
      int c = ks * 4 + lk;
      short8 av[4];
#pragma unroll
      for (int mf = 0; mf < 4; ++mf) {
        int row = wm * 64 + mf * 16 + lm;
        av[mf] = *(short8*)&a_s[row][(c ^ (row & 7)) << 3];
      }
      int n0 = wn * 32 + lm;
      int sw = (c ^ (n0 & 7)) << 3;
      short8 b0 = *(short8*)&b_s[n0][sw];
      short8 b1 = *(short8*)&b_s[n0 + 16][sw];
#pragma unroll
      for (int mf = 0; mf < 4; ++mf) {
        acc[mf][0] = __builtin_amdgcn_mfma_f32_16x16x32_bf16(av[mf], b0, acc[mf][0], 0, 0, 0);
        acc[mf][1] = __builtin_amdgcn_mfma_f32_16x16x32_bf16(av[mf], b1, acc[mf][1], 0, 0, 0);
      }
    }
    __syncthreads();
  }
#pragma unroll
  for (int mf = 0; mf < 4; ++mf)
#pragma unroll
    for (int nf = 0; nf < 2; ++nf)
#pragma unroll
      for (int r = 0; r < 4; ++r) {
        int lrow = wm * 64 + mf * 16 + lk * 4 + r;
        if (lrow < rloc) {
          int t = tok_s[lrow];
          atomicAdd(&out[(size_t)t * DDIM + nb + wn * 32 + nf * 16 + lm],
                    w_s[lrow] * acc[mf][nf][r]);
        }
      }
}

extern "C" void kernel_launch(void* const* d_in, const int* in_sizes, int n_in,
                              void* d_out, int out_size, void* d_ws, size_t ws_size,
                              hipStream_t stream) {
  const float* x    = (const float*)d_in[0];
  const float* gw   = (const float*)d_in[1];
  const float* bias = (const float*)d_in[2];
  const float* wg   = (const float*)d_in[3];
  const float* wu   = (const float*)d_in[4];
  const float* wd   = (const float*)d_in[5];
  const float* wsg  = (const float*)d_in[6];
  const float* wsu  = (const float*)d_in[7];
  const float* wsd  = (const float*)d_in[8];
  float* out = (float*)d_out;
  int* ws = (int*)d_ws;
  __hip_bfloat16* H = (__hip_bfloat16*)((char*)d_ws + (size_t)WS_H * 4);

  hipMemsetAsync(d_out, 0, (size_t)out_size * sizeof(float), stream);
  hipMemsetAsync(d_ws, 0, 32 * sizeof(int), stream);   // zero expert counts
  k_router<<<T_TOK, 64, 0, stream>>>(x, gw, bias, ws);
  k_post<<<1, 1024, 0, stream>>>(ws, out);
  // max tiles at BM=256: routed sum ceil(n_e/256) <= 16+32=48, +4 shared => 52; 64 is safe
  k_stage1<<<dim3(64, 32), 512, 0, stream>>>(x, wg, wu, wsg, wsu, ws, H);
  k_stage2<<<dim3(64, 16), 512, 0, stream>>>(wd, wsd, ws, H, out);
}